// Round 4
// baseline (268.391 us; speedup 1.0000x reference)
//
#include <hip/hip_runtime.h>
#include <math.h>

#define LTOT 2048
#define MROWS 4096   // BATCH * LTOT
#define CHK 64
#define NCH (LTOT / CHK)   // 32
#define SPAD 20

typedef short bf16x8 __attribute__((ext_vector_type(8)));
typedef float f32x16 __attribute__((ext_vector_type(16)));

__device__ __forceinline__ unsigned short bf16_rne(float f) {
  unsigned u = __float_as_uint(f);
  u += 0x7FFF + ((u >> 16) & 1);
  return (unsigned short)(u >> 16);
}
__device__ __forceinline__ float bf16_to_f(unsigned short h) {
  return __uint_as_float(((unsigned)h) << 16);
}
__device__ __forceinline__ float softplus_f(float x) {
  return (x > 15.f) ? x : log1pf(expf(x));
}
__device__ __forceinline__ float silu_f(float x) {
  return x / (1.f + expf(-x));
}

// ---------------------------------------------------------------------------
// fp32 -> (hi, lo) bf16 split, elementwise (4 elems/thread).
// ---------------------------------------------------------------------------
__global__ void k_cvt(const float* __restrict__ src, unsigned short* __restrict__ h,
                      unsigned short* __restrict__ l, int n4) {
  const int i = blockIdx.x * 256 + threadIdx.x;
  if (i >= n4) return;
  const float4 v = ((const float4*)src)[i];
  ushort4 hh, ll;
  hh.x = bf16_rne(v.x); ll.x = bf16_rne(v.x - bf16_to_f(hh.x));
  hh.y = bf16_rne(v.y); ll.y = bf16_rne(v.y - bf16_to_f(hh.y));
  hh.z = bf16_rne(v.z); ll.z = bf16_rne(v.z - bf16_to_f(hh.z));
  hh.w = bf16_rne(v.w); ll.w = bf16_rne(v.w - bf16_to_f(hh.w));
  ((ushort4*)h)[i] = hh;
  ((ushort4*)l)[i] = ll;
}

// ---------------------------------------------------------------------------
// Transposed split of W1u: out[k][j] = W1[j][k], j,k < 1024, hi/lo bf16.
// ---------------------------------------------------------------------------
__global__ __launch_bounds__(256) void k_cvt_t(const float* __restrict__ w1,
    unsigned short* __restrict__ th, unsigned short* __restrict__ tl) {
  __shared__ float ts[64][65];
  const int t = threadIdx.x;
  const int j0 = blockIdx.y * 64, k0 = blockIdx.x * 64;
  const int r = t >> 4, c4 = (t & 15) * 4;
  #pragma unroll
  for (int p = 0; p < 4; ++p) {
    const int row = p * 16 + r;
    const float4 v = *(const float4*)&w1[(size_t)(j0 + row) * 1024 + k0 + c4];
    ts[row][c4] = v.x; ts[row][c4+1] = v.y; ts[row][c4+2] = v.z; ts[row][c4+3] = v.w;
  }
  __syncthreads();
  #pragma unroll
  for (int p = 0; p < 4; ++p) {
    const int rk = p * 16 + r;
    ushort4 hh, ll;
    float f;
    f = ts[c4+0][rk]; hh.x = bf16_rne(f); ll.x = bf16_rne(f - bf16_to_f(hh.x));
    f = ts[c4+1][rk]; hh.y = bf16_rne(f); ll.y = bf16_rne(f - bf16_to_f(hh.y));
    f = ts[c4+2][rk]; hh.z = bf16_rne(f); ll.z = bf16_rne(f - bf16_to_f(hh.z));
    f = ts[c4+3][rk]; hh.w = bf16_rne(f); ll.w = bf16_rne(f - bf16_to_f(hh.w));
    *(ushort4*)&th[(size_t)(k0 + rk) * 1024 + j0 + c4] = hh;
    *(ushort4*)&tl[(size_t)(k0 + rk) * 1024 + j0 + c4] = ll;
  }
}

// ---------------------------------------------------------------------------
// bfull[j] = sum_k b1[k] * Wdb[j,k] + (j>=1024 ? bb[j-1024] : 0),  j < 1152
// block = 256 thr = 16 groups of 16 lanes; group per output j. grid = 72.
// ---------------------------------------------------------------------------
__global__ void k_bias(const float* __restrict__ b1, const float* __restrict__ dw,
                       const float* __restrict__ bw, const float* __restrict__ bb,
                       float* __restrict__ bfull) {
  const int t = threadIdx.x;
  const int j = blockIdx.x * 16 + (t >> 4);
  const int lane16 = t & 15;
  const float* W = (j < 1024) ? (dw + (size_t)j * 1024) : (bw + (size_t)(j - 1024) * 1024);
  float s = 0.f;
  for (int i = 0; i < 64; ++i) {
    const int k = lane16 + i * 16;
    s = fmaf(b1[k], W[k], s);
  }
  s += __shfl_xor(s, 8, 16);
  s += __shfl_xor(s, 4, 16);
  s += __shfl_xor(s, 2, 16);
  s += __shfl_xor(s, 1, 16);
  if (lane16 == 0) bfull[j] = s + ((j >= 1024) ? bb[j - 1024] : 0.f);
}

// ---------------------------------------------------------------------------
// Weight composition GEMM: C[i,k] = sum_j Wdb[i,j] * W1uT[k,j]  (split bf16 out)
// M=1152, N=1024, K=1024. 64x64 tiles, 4 waves of 32x32. grid (16, 18).
// ---------------------------------------------------------------------------
__global__ __launch_bounds__(256) void k_wcomp(
    const unsigned short* __restrict__ Ah_g, const unsigned short* __restrict__ Al_g,
    const unsigned short* __restrict__ Bh_g, const unsigned short* __restrict__ Bl_g,
    unsigned short* __restrict__ outh, unsigned short* __restrict__ outl) {
  __shared__ __align__(16) unsigned short LAh[64*32];
  __shared__ __align__(16) unsigned short LAl[64*32];
  __shared__ __align__(16) unsigned short LBh[64*32];
  __shared__ __align__(16) unsigned short LBl[64*32];
  const int t = threadIdx.x;
  const int wave = t >> 6, lane = t & 63;
  const int m0 = blockIdx.y * 64, n0 = blockIdx.x * 64;
  const int wr = wave >> 1, wc = wave & 1;
  const int l32 = lane & 31, hi = lane >> 5;
  const int srow = lane >> 2, scol = (lane & 3) * 8;

  f32x16 acc;
  #pragma unroll
  for (int q = 0; q < 16; ++q) acc[q] = 0.f;

  auto stage = [&](const unsigned short* g, unsigned short* lds, int rbase, int k0) {
    const unsigned short* gp = g + (size_t)(rbase + wave * 16 + srow) * 1024 + k0 + scol;
    unsigned short* lp = lds + (wave * 16) * 32;
    __builtin_amdgcn_global_load_lds((const __attribute__((address_space(1))) void*)gp,
                                     (__attribute__((address_space(3))) void*)lp, 16, 0, 0);
  };

  for (int k0 = 0; k0 < 1024; k0 += 32) {
    __syncthreads();
    stage(Ah_g, LAh, m0, k0);
    stage(Al_g, LAl, m0, k0);
    stage(Bh_g, LBh, n0, k0);
    stage(Bl_g, LBl, n0, k0);
    __syncthreads();
    #pragma unroll
    for (int kh = 0; kh < 2; ++kh) {
      const int ai = (wr * 32 + l32) * 32 + kh * 16 + hi * 8;
      const int bi = (wc * 32 + l32) * 32 + kh * 16 + hi * 8;
      bf16x8 a_h = *(const bf16x8*)&LAh[ai];
      bf16x8 a_l = *(const bf16x8*)&LAl[ai];
      bf16x8 b_h = *(const bf16x8*)&LBh[bi];
      bf16x8 b_l = *(const bf16x8*)&LBl[bi];
      acc = __builtin_amdgcn_mfma_f32_32x32x16_bf16(a_h, b_h, acc, 0, 0, 0);
      acc = __builtin_amdgcn_mfma_f32_32x32x16_bf16(a_h, b_l, acc, 0, 0, 0);
      acc = __builtin_amdgcn_mfma_f32_32x32x16_bf16(a_l, b_h, acc, 0, 0, 0);
    }
  }

  #pragma unroll
  for (int reg = 0; reg < 16; ++reg) {
    const int i = m0 + wr * 32 + (reg & 3) + 8 * (reg >> 2) + 4 * hi;
    const int k = n0 + wc * 32 + l32;
    const float f = acc[reg];
    const unsigned short hh = bf16_rne(f);
    const unsigned short ll = bf16_rne(f - bf16_to_f(hh));
    outh[(size_t)i * 1024 + k] = hh;
    outl[(size_t)i * 1024 + k] = ll;
  }
}

// ---------------------------------------------------------------------------
// Main GEMM: C = x . Wfull^T, Wfull = [W_in(2048) ; Wd'(1024) ; Wb'(128)], N=3200
// 128x128 tile, BK=32, 4 waves of 64x64 (2x2 frags of 32x32x16), split-bf16.
// Epilogue by n-tile: u(+b1), v(+b1), delta(softplus(+bd')), Bm(+bB').
// ---------------------------------------------------------------------------
__global__ __launch_bounds__(256) void k_main(
    const unsigned short* __restrict__ xh, const unsigned short* __restrict__ xl,
    const unsigned short* __restrict__ wfh, const unsigned short* __restrict__ wfl,
    const float* __restrict__ b1, const float* __restrict__ bfull,
    float* __restrict__ u_, float* __restrict__ v_,
    float* __restrict__ delta, float* __restrict__ Bm) {
  __shared__ __align__(16) unsigned short LAh[128*32];
  __shared__ __align__(16) unsigned short LAl[128*32];
  __shared__ __align__(16) unsigned short LBh[128*32];
  __shared__ __align__(16) unsigned short LBl[128*32];
  const int t = threadIdx.x;
  const int wave = t >> 6, lane = t & 63;
  const int tn = blockIdx.x;
  const int m0 = blockIdx.y * 128;
  const int wr = wave >> 1, wc = wave & 1;
  const int l32 = lane & 31, hi = lane >> 5;
  const int srow = lane >> 2, scol = (lane & 3) * 8;

  f32x16 acc[2][2];
  {
    f32x16 vz;
    #pragma unroll
    for (int q = 0; q < 16; ++q) vz[q] = 0.f;
    acc[0][0] = vz; acc[0][1] = vz; acc[1][0] = vz; acc[1][1] = vz;
  }

  const unsigned short* pAh = xh + (size_t)m0 * 1024;
  const unsigned short* pAl = xl + (size_t)m0 * 1024;
  const unsigned short* pBh = wfh + (size_t)(tn * 128) * 1024;
  const unsigned short* pBl = wfl + (size_t)(tn * 128) * 1024;

  auto stage = [&](const unsigned short* g, unsigned short* lds, int k0) {
    #pragma unroll
    for (int r = 0; r < 2; ++r) {
      const unsigned short* gp = g + (size_t)(r * 64 + wave * 16 + srow) * 1024 + k0 + scol;
      unsigned short* lp = lds + (r * 64 + wave * 16) * 32;
      __builtin_amdgcn_global_load_lds((const __attribute__((address_space(1))) void*)gp,
                                       (__attribute__((address_space(3))) void*)lp, 16, 0, 0);
    }
  };

  for (int k0 = 0; k0 < 1024; k0 += 32) {
    __syncthreads();
    stage(pAh, LAh, k0);
    stage(pAl, LAl, k0);
    stage(pBh, LBh, k0);
    stage(pBl, LBl, k0);
    __syncthreads();
    #pragma unroll
    for (int kh = 0; kh < 2; ++kh) {
      bf16x8 ah[2], al[2], bh[2], bl[2];
      #pragma unroll
      for (int mi = 0; mi < 2; ++mi) {
        const int ai = (wr * 64 + mi * 32 + l32) * 32 + kh * 16 + hi * 8;
        ah[mi] = *(const bf16x8*)&LAh[ai];
        al[mi] = *(const bf16x8*)&LAl[ai];
      }
      #pragma unroll
      for (int nj = 0; nj < 2; ++nj) {
        const int bi = (wc * 64 + nj * 32 + l32) * 32 + kh * 16 + hi * 8;
        bh[nj] = *(const bf16x8*)&LBh[bi];
        bl[nj] = *(const bf16x8*)&LBl[bi];
      }
      #pragma unroll
      for (int mi = 0; mi < 2; ++mi)
        #pragma unroll
        for (int nj = 0; nj < 2; ++nj) {
          acc[mi][nj] = __builtin_amdgcn_mfma_f32_32x32x16_bf16(ah[mi], bh[nj], acc[mi][nj], 0, 0, 0);
          acc[mi][nj] = __builtin_amdgcn_mfma_f32_32x32x16_bf16(ah[mi], bl[nj], acc[mi][nj], 0, 0, 0);
          acc[mi][nj] = __builtin_amdgcn_mfma_f32_32x32x16_bf16(al[mi], bh[nj], acc[mi][nj], 0, 0, 0);
        }
    }
  }

  #pragma unroll
  for (int nj = 0; nj < 2; ++nj) {
    const int colg = tn * 128 + wc * 64 + nj * 32 + l32;
    const float bv = (tn < 16) ? b1[colg] : bfull[colg - 2048];
    #pragma unroll
    for (int mi = 0; mi < 2; ++mi) {
      #pragma unroll
      for (int reg = 0; reg < 16; ++reg) {
        const int row = m0 + wr * 64 + mi * 32 + (reg & 3) + 8 * (reg >> 2) + 4 * hi;
        const float val = acc[mi][nj][reg] + bv;
        if (tn < 8)       u_[(size_t)row * 1024 + colg] = val;
        else if (tn < 16) v_[(size_t)row * 1024 + colg - 1024] = val;
        else if (tn < 24) delta[(size_t)row * 1024 + colg - 2048] = softplus_f(val);
        else              Bm[(size_t)row * 128 + colg - 3072] = val;
      }
    }
  }
}

// ---------------------------------------------------------------------------
// Chunk-parallel selective scan with fused depthwise conv+silu.
// ---------------------------------------------------------------------------
__global__ __launch_bounds__(256) void k_scanA(
    const float* __restrict__ delta, const float* __restrict__ u_,
    const float* __restrict__ Bm, const float* __restrict__ a_log,
    const float* __restrict__ cw, const float* __restrict__ cb,
    float* __restrict__ hend, float* __restrict__ Pp)
{
  __shared__ float sru[68][SPAD];
  __shared__ float sd[CHK][SPAD];
  __shared__ float sb[CHK][SPAD];
  __shared__ float suc[CHK][SPAD];
  const int t = threadIdx.x;
  const int bid = blockIdx.x;
  const int dblk = bid & 63;
  const int ch   = (bid >> 6) & (NCH - 1);
  const int b    = bid >> 11;
  const int d0 = dblk * 16;
  const int g  = dblk >> 3;
  const int l0 = ch * CHK;
  const size_t mb = (size_t)b * LTOT;

  {
    const int lrow = t >> 2;
    const int lc4  = (t & 3) * 4;
    const size_t r = mb + l0 + lrow;
    float4 rd = *(const float4*)&delta[r*1024 + d0 + lc4];
    float4 rb = *(const float4*)&Bm[r*128 + g*16 + lc4];
    *(float4*)&sd[lrow][lc4] = rd;
    *(float4*)&sb[lrow][lc4] = rb;
    const int sl = l0 + lrow - 4;
    float4 ru = (sl >= 0) ? *(const float4*)&u_[(mb + sl)*1024 + d0 + lc4]
                          : (float4){0.f, 0.f, 0.f, 0.f};
    *(float4*)&sru[lrow][lc4] = ru;
    if (t < 16) {
      const int rr2 = 64 + (t >> 2);
      const int sl2 = l0 + rr2 - 4;
      float4 r2 = *(const float4*)&u_[(mb + sl2)*1024 + d0 + (t & 3) * 4];
      *(float4*)&sru[rr2][(t & 3) * 4] = r2;
    }
  }
  __syncthreads();
  {
    const int c = t & 15;
    const int rb4 = (t >> 4) * 4;
    const float4 cwf = *(const float4*)&cw[(d0 + c) * 4];
    const float cbf = cb[d0 + c];
    #pragma unroll
    for (int q = 0; q < 4; ++q) {
      const int l = rb4 + q;
      float a = cbf;
      a = fmaf(sru[l+1][c], cwf.x, a);
      a = fmaf(sru[l+2][c], cwf.y, a);
      a = fmaf(sru[l+3][c], cwf.z, a);
      a = fmaf(sru[l+4][c], cwf.w, a);
      suc[l][c] = silu_f(a);
    }
  }
  __syncthreads();

  const int gi = t >> 4;
  const int n  = t & 15;
  const int d  = d0 + gi;
  const float A2 = -expf(a_log[d*16 + n]) * 1.4426950408889634f;

  float h = 0.f, P = 1.f;
  #pragma unroll 8
  for (int l = 0; l < CHK; ++l) {
    const float dv = sd[l][gi];
    const float uv = suc[l][gi];
    const float bv = sb[l][n];
    const float da = exp2f(dv * A2);
    P *= da;
    h = fmaf(da, h, dv * uv * bv);
  }
  const size_t idx = ((size_t)(b*NCH + ch) * 1024 + d) * 16 + n;
  hend[idx] = h;
  Pp[idx]   = P;
}

__global__ void k_scanB(float* hP, const float* __restrict__ Pp)
{
  const int t = blockIdx.x * 256 + threadIdx.x;   // 32768 strands
  const int b  = t >> 14;
  const int dn = t & 16383;
  float H = 0.f;
  for (int ch = 0; ch < NCH; ++ch) {
    const size_t idx = ((size_t)(b*NCH + ch) << 14) + dn;
    const float he = hP[idx];
    const float P  = Pp[idx];
    hP[idx] = H;
    H = fmaf(P, H, he);
  }
}

__global__ __launch_bounds__(256) void k_scanC(
    const float* __restrict__ v_, const float* __restrict__ delta,
    const float* __restrict__ u_, const float* __restrict__ Bm,
    const float* __restrict__ a_log, const float* __restrict__ cp,
    const float* __restrict__ cw, const float* __restrict__ cb,
    const float* __restrict__ Hstart, float* __restrict__ out)
{
  __shared__ float sru[68][SPAD];
  __shared__ float sd[CHK][SPAD];
  __shared__ float sb[CHK][SPAD];
  __shared__ float suc[CHK][SPAD];
  __shared__ float sv[CHK][SPAD];
  __shared__ float sy[CHK][SPAD];
  const int t = threadIdx.x;
  const int bid = blockIdx.x;
  const int dblk = bid & 63;
  const int ch   = (bid >> 6) & (NCH - 1);
  const int b    = bid >> 11;
  const int d0 = dblk * 16;
  const int g  = dblk >> 3;
  const int l0 = ch * CHK;
  const size_t mb = (size_t)b * LTOT;

  {
    const int lrow = t >> 2;
    const int lc4  = (t & 3) * 4;
    const size_t r = mb + l0 + lrow;
    float4 rd = *(const float4*)&delta[r*1024 + d0 + lc4];
    float4 rb = *(const float4*)&Bm[r*128 + g*16 + lc4];
    float4 rv = *(const float4*)&v_[r*1024 + d0 + lc4];
    *(float4*)&sd[lrow][lc4] = rd;
    *(float4*)&sb[lrow][lc4] = rb;
    *(float4*)&sv[lrow][lc4] = rv;
    const int sl = l0 + lrow - 4;
    float4 ru = (sl >= 0) ? *(const float4*)&u_[(mb + sl)*1024 + d0 + lc4]
                          : (float4){0.f, 0.f, 0.f, 0.f};
    *(float4*)&sru[lrow][lc4] = ru;
    if (t < 16) {
      const int rr2 = 64 + (t >> 2);
      const int sl2 = l0 + rr2 - 4;
      float4 r2 = *(const float4*)&u_[(mb + sl2)*1024 + d0 + (t & 3) * 4];
      *(float4*)&sru[rr2][(t & 3) * 4] = r2;
    }
  }
  __syncthreads();
  {
    const int c = t & 15;
    const int rb4 = (t >> 4) * 4;
    const float4 cwf = *(const float4*)&cw[(d0 + c) * 4];
    const float cbf = cb[d0 + c];
    #pragma unroll
    for (int q = 0; q < 4; ++q) {
      const int l = rb4 + q;
      float a = cbf;
      a = fmaf(sru[l+1][c], cwf.x, a);
      a = fmaf(sru[l+2][c], cwf.y, a);
      a = fmaf(sru[l+3][c], cwf.z, a);
      a = fmaf(sru[l+4][c], cwf.w, a);
      suc[l][c] = silu_f(a);
    }
  }
  __syncthreads();

  const int gi = t >> 4;
  const int n  = t & 15;
  const int d  = d0 + gi;
  const float A2 = -expf(a_log[d*16 + n]) * 1.4426950408889634f;
  const float cc = cp[d*16 + n];
  float h = Hstart[((size_t)(b*NCH + ch) * 1024 + d) * 16 + n];

  #pragma unroll
  for (int l16 = 0; l16 < CHK; l16 += 16) {
    float p[16];
    #pragma unroll
    for (int j = 0; j < 16; ++j) {
      const int l = l16 + j;
      const float dv = sd[l][gi];
      const float uv = suc[l][gi];
      const float bv = sb[l][n];
      const float da = exp2f(dv * A2);
      h = fmaf(da, h, dv * uv * bv);
      p[j] = h * cc;
    }
    float q8[8];
    #pragma unroll
    for (int j = 0; j < 8; ++j) {
      const float send = (n & 8) ? p[j]     : p[j + 8];
      const float keep = (n & 8) ? p[j + 8] : p[j];
      q8[j] = keep + __shfl_xor(send, 8, 16);
    }
    float q4[4];
    #pragma unroll
    for (int j = 0; j < 4; ++j) {
      const float send = (n & 4) ? q8[j]     : q8[j + 4];
      const float keep = (n & 4) ? q8[j + 4] : q8[j];
      q4[j] = keep + __shfl_xor(send, 4, 16);
    }
    float q2[2];
    #pragma unroll
    for (int j = 0; j < 2; ++j) {
      const float send = (n & 2) ? q4[j]     : q4[j + 2];
      const float keep = (n & 2) ? q4[j + 2] : q4[j];
      q2[j] = keep + __shfl_xor(send, 2, 16);
    }
    {
      const float send = (n & 1) ? q2[0] : q2[1];
      const float keep = (n & 1) ? q2[1] : q2[0];
      sy[l16 + n][gi] = keep + __shfl_xor(send, 1, 16);
    }
  }

  __syncthreads();
  const int rr = t >> 4;
  const int c  = t & 15;
  #pragma unroll
  for (int k = 0; k < 4; ++k) {
    const int r = rr + k * 16;
    const float vv = sv[r][c];
    out[(mb + l0 + r) * 1024 + d0 + c] = sy[r][c] * silu_f(vv);
  }
}

// ---------------------------------------------------------------------------
extern "C" void kernel_launch(void* const* d_in, const int* in_sizes, int n_in,
                              void* d_out, int out_size, void* d_ws, size_t ws_size,
                              hipStream_t stream) {
  const float* x    = (const float*)d_in[0];
  const float* w1   = (const float*)d_in[1];
  const float* b1   = (const float*)d_in[2];
  const float* dw   = (const float*)d_in[3];
  const float* alog = (const float*)d_in[4];
  const float* bw   = (const float*)d_in[5];
  const float* bb   = (const float*)d_in[6];
  const float* cp   = (const float*)d_in[7];
  const float* cw   = (const float*)d_in[8];
  const float* cb   = (const float*)d_in[9];
  float* out = (float*)d_out;

  const size_t M4 = (size_t)MROWS * 1024;             // 4,194,304
  float* u_    = (float*)d_ws;                        // [4096][1024] 16 MB
  float* v_    = u_ + M4;                             // 16 MB
  float* delta = v_ + M4;                             // 16 MB
  float* Bm    = delta + M4;                          // [4096][128]   2 MB
  unsigned short* xh  = (unsigned short*)(Bm + (size_t)MROWS * 128);
  unsigned short* xl  = xh + M4;
  unsigned short* wfh = xl + M4;                      // [3200][1024]  6.25 MB
  unsigned short* wfl = wfh + (size_t)3200 * 1024;
  float* bfull = (float*)(wfl + (size_t)3200 * 1024); // [1152]
  // pre-main aliases (dead before their regions are written):
  unsigned short* wdbAh = (unsigned short*)delta;     // [1152][1024] in delta region
  unsigned short* wdbAl = wdbAh + (size_t)1152 * 1024;
  unsigned short* w1th  = wdbAl + (size_t)1152 * 1024;
  unsigned short* w1tl  = w1th + (size_t)1024 * 1024; // total 8.5 MB <= 16 MB
  // post-main aliases (wfull dead after k_main):
  float* hend = (float*)wfh;                          // 4 MB
  float* Pp   = hend + (size_t)2 * NCH * 1024 * 16;   // 4 MB (<= 12.5 MB region)

  k_cvt<<<4096, 256, 0, stream>>>(x,  xh, xl, 1048576);
  k_cvt<<<2048, 256, 0, stream>>>(w1, wfh, wfl, 524288);
  k_cvt<<<1024, 256, 0, stream>>>(dw, wdbAh, wdbAl, 262144);
  k_cvt<<<128, 256, 0, stream>>>(bw, wdbAh + (size_t)1024*1024, wdbAl + (size_t)1024*1024, 32768);
  k_cvt_t<<<dim3(16, 16), 256, 0, stream>>>(w1, w1th, w1tl);
  k_bias<<<72, 256, 0, stream>>>(b1, dw, bw, bb, bfull);
  k_wcomp<<<dim3(16, 18), 256, 0, stream>>>(wdbAh, wdbAl, w1th, w1tl,
                                            wfh + (size_t)2048*1024, wfl + (size_t)2048*1024);
  k_main<<<dim3(25, 32), 256, 0, stream>>>(xh, xl, wfh, wfl, b1, bfull, u_, v_, delta, Bm);
  k_scanA<<<2 * NCH * 64, 256, 0, stream>>>(delta, u_, Bm, alog, cw, cb, hend, Pp);
  k_scanB<<<128, 256, 0, stream>>>(hend, Pp);
  k_scanC<<<2 * NCH * 64, 256, 0, stream>>>(v_, delta, u_, Bm, alog, cp, cw, cb, hend, out);
}

// Round 5
// 245.198 us; speedup vs baseline: 1.0946x; 1.0946x over previous
//
#include <hip/hip_runtime.h>
#include <math.h>

#define LTOT 2048
#define MROWS 4096   // BATCH * LTOT
#define CHK 64
#define NCH (LTOT / CHK)   // 32
#define SPAD 20

typedef short bf16x8 __attribute__((ext_vector_type(8)));
typedef float f32x4  __attribute__((ext_vector_type(4)));
typedef float f32x16 __attribute__((ext_vector_type(16)));

__device__ __forceinline__ unsigned short bf16_rne(float f) {
  unsigned u = __float_as_uint(f);
  u += 0x7FFF + ((u >> 16) & 1);
  return (unsigned short)(u >> 16);
}
__device__ __forceinline__ float bf16_to_f(unsigned short h) {
  return __uint_as_float(((unsigned)h) << 16);
}
__device__ __forceinline__ float softplus_f(float x) {
  return (x > 15.f) ? x : log1pf(expf(x));
}
__device__ __forceinline__ float silu_f(float x) {
  return x / (1.f + expf(-x));
}

// ---------------------------------------------------------------------------
// fp32 -> (hi, lo) bf16 split, elementwise (4 elems/thread).
// ---------------------------------------------------------------------------
__global__ void k_cvt(const float* __restrict__ src, unsigned short* __restrict__ h,
                      unsigned short* __restrict__ l, int n4) {
  const int i = blockIdx.x * 256 + threadIdx.x;
  if (i >= n4) return;
  const float4 v = ((const float4*)src)[i];
  ushort4 hh, ll;
  hh.x = bf16_rne(v.x); ll.x = bf16_rne(v.x - bf16_to_f(hh.x));
  hh.y = bf16_rne(v.y); ll.y = bf16_rne(v.y - bf16_to_f(hh.y));
  hh.z = bf16_rne(v.z); ll.z = bf16_rne(v.z - bf16_to_f(hh.z));
  hh.w = bf16_rne(v.w); ll.w = bf16_rne(v.w - bf16_to_f(hh.w));
  ((ushort4*)h)[i] = hh;
  ((ushort4*)l)[i] = ll;
}

// ---------------------------------------------------------------------------
// Transposed split of W1u: out[k][j] = W1[j][k], j,k < 1024, hi/lo bf16.
// ---------------------------------------------------------------------------
__global__ __launch_bounds__(256) void k_cvt_t(const float* __restrict__ w1,
    unsigned short* __restrict__ th, unsigned short* __restrict__ tl) {
  __shared__ float ts[64][65];
  const int t = threadIdx.x;
  const int j0 = blockIdx.y * 64, k0 = blockIdx.x * 64;
  const int r = t >> 4, c4 = (t & 15) * 4;
  #pragma unroll
  for (int p = 0; p < 4; ++p) {
    const int row = p * 16 + r;
    const float4 v = *(const float4*)&w1[(size_t)(j0 + row) * 1024 + k0 + c4];
    ts[row][c4] = v.x; ts[row][c4+1] = v.y; ts[row][c4+2] = v.z; ts[row][c4+3] = v.w;
  }
  __syncthreads();
  #pragma unroll
  for (int p = 0; p < 4; ++p) {
    const int rk = p * 16 + r;
    ushort4 hh, ll;
    float f;
    f = ts[c4+0][rk]; hh.x = bf16_rne(f); ll.x = bf16_rne(f - bf16_to_f(hh.x));
    f = ts[c4+1][rk]; hh.y = bf16_rne(f); ll.y = bf16_rne(f - bf16_to_f(hh.y));
    f = ts[c4+2][rk]; hh.z = bf16_rne(f); ll.z = bf16_rne(f - bf16_to_f(hh.z));
    f = ts[c4+3][rk]; hh.w = bf16_rne(f); ll.w = bf16_rne(f - bf16_to_f(hh.w));
    *(ushort4*)&th[(size_t)(k0 + rk) * 1024 + j0 + c4] = hh;
    *(ushort4*)&tl[(size_t)(k0 + rk) * 1024 + j0 + c4] = ll;
  }
}

// ---------------------------------------------------------------------------
// bfull[j] = sum_k b1[k] * Wdb[j,k] + (j>=1024 ? bb[j-1024] : 0),  j < 1152
// ---------------------------------------------------------------------------
__global__ void k_bias(const float* __restrict__ b1, const float* __restrict__ dw,
                       const float* __restrict__ bw, const float* __restrict__ bb,
                       float* __restrict__ bfull) {
  const int t = threadIdx.x;
  const int j = blockIdx.x * 16 + (t >> 4);
  const int lane16 = t & 15;
  const float* W = (j < 1024) ? (dw + (size_t)j * 1024) : (bw + (size_t)(j - 1024) * 1024);
  float s = 0.f;
  for (int i = 0; i < 64; ++i) {
    const int k = lane16 + i * 16;
    s = fmaf(b1[k], W[k], s);
  }
  s += __shfl_xor(s, 8, 16);
  s += __shfl_xor(s, 4, 16);
  s += __shfl_xor(s, 2, 16);
  s += __shfl_xor(s, 1, 16);
  if (lane16 == 0) bfull[j] = s + ((j >= 1024) ? bb[j - 1024] : 0.f);
}

// ---------------------------------------------------------------------------
// Weight composition GEMM: C[i,k] = sum_j Wdb[i,j] * W1uT[k,j]  (split bf16 out)
// M=1152, N=1024, K=1024. 64x64 tiles, 4 waves of 32x32. grid (16, 18).
// ---------------------------------------------------------------------------
__global__ __launch_bounds__(256) void k_wcomp(
    const unsigned short* __restrict__ Ah_g, const unsigned short* __restrict__ Al_g,
    const unsigned short* __restrict__ Bh_g, const unsigned short* __restrict__ Bl_g,
    unsigned short* __restrict__ outh, unsigned short* __restrict__ outl) {
  __shared__ __align__(16) unsigned short LAh[64*32];
  __shared__ __align__(16) unsigned short LAl[64*32];
  __shared__ __align__(16) unsigned short LBh[64*32];
  __shared__ __align__(16) unsigned short LBl[64*32];
  const int t = threadIdx.x;
  const int wave = t >> 6, lane = t & 63;
  const int m0 = blockIdx.y * 64, n0 = blockIdx.x * 64;
  const int wr = wave >> 1, wc = wave & 1;
  const int l32 = lane & 31, hi = lane >> 5;
  const int srow = lane >> 2, scol = (lane & 3) * 8;

  f32x16 acc;
  #pragma unroll
  for (int q = 0; q < 16; ++q) acc[q] = 0.f;

  auto stage = [&](const unsigned short* g, unsigned short* lds, int rbase, int k0) {
    const unsigned short* gp = g + (size_t)(rbase + wave * 16 + srow) * 1024 + k0 + scol;
    unsigned short* lp = lds + (wave * 16) * 32;
    __builtin_amdgcn_global_load_lds((const __attribute__((address_space(1))) void*)gp,
                                     (__attribute__((address_space(3))) void*)lp, 16, 0, 0);
  };

  for (int k0 = 0; k0 < 1024; k0 += 32) {
    __syncthreads();
    stage(Ah_g, LAh, m0, k0);
    stage(Al_g, LAl, m0, k0);
    stage(Bh_g, LBh, n0, k0);
    stage(Bl_g, LBl, n0, k0);
    __syncthreads();
    #pragma unroll
    for (int kh = 0; kh < 2; ++kh) {
      const int ai = (wr * 32 + l32) * 32 + kh * 16 + hi * 8;
      const int bi = (wc * 32 + l32) * 32 + kh * 16 + hi * 8;
      bf16x8 a_h = *(const bf16x8*)&LAh[ai];
      bf16x8 a_l = *(const bf16x8*)&LAl[ai];
      bf16x8 b_h = *(const bf16x8*)&LBh[bi];
      bf16x8 b_l = *(const bf16x8*)&LBl[bi];
      acc = __builtin_amdgcn_mfma_f32_32x32x16_bf16(a_h, b_h, acc, 0, 0, 0);
      acc = __builtin_amdgcn_mfma_f32_32x32x16_bf16(a_h, b_l, acc, 0, 0, 0);
      acc = __builtin_amdgcn_mfma_f32_32x32x16_bf16(a_l, b_h, acc, 0, 0, 0);
    }
  }

  #pragma unroll
  for (int reg = 0; reg < 16; ++reg) {
    const int i = m0 + wr * 32 + (reg & 3) + 8 * (reg >> 2) + 4 * hi;
    const int k = n0 + wc * 32 + l32;
    const float f = acc[reg];
    const unsigned short hh = bf16_rne(f);
    const unsigned short ll = bf16_rne(f - bf16_to_f(hh));
    outh[(size_t)i * 1024 + k] = hh;
    outl[(size_t)i * 1024 + k] = ll;
  }
}

// ---------------------------------------------------------------------------
// Main GEMM: C = x . Wfull^T, Wfull = [W_in(2048) ; Wd'(1024) ; Wb'(128)], N=3200
// 128x128 tile, BK=32, 4 waves (2x2), 4x4 frags of 16x16x32 (round-3 proven
// layout: 2.4e6 bank conflicts vs 2e7 for the 32x32 pattern).
// tn<16 (u,v): 2-product split (drop W-lo; linear error path tolerates bf16-w).
// tn>=16 (delta,B): full 3-product split (exp(dA) amplifies by |A|<=16).
// ---------------------------------------------------------------------------
__global__ __launch_bounds__(256) void k_main(
    const unsigned short* __restrict__ xh, const unsigned short* __restrict__ xl,
    const unsigned short* __restrict__ wfh, const unsigned short* __restrict__ wfl,
    const float* __restrict__ b1, const float* __restrict__ bfull,
    float* __restrict__ u_, float* __restrict__ v_,
    float* __restrict__ delta, float* __restrict__ Bm) {
  __shared__ __align__(16) unsigned short LAh[128*32];
  __shared__ __align__(16) unsigned short LAl[128*32];
  __shared__ __align__(16) unsigned short LBh[128*32];
  __shared__ __align__(16) unsigned short LBl[128*32];
  const int t = threadIdx.x;
  const int wave = t >> 6, lane = t & 63;
  const int tn = blockIdx.x;
  const int m0 = blockIdx.y * 128;
  const int wr = wave >> 1, wc = wave & 1;
  const int ln = lane & 15, kq = lane >> 4;
  const int srow = lane >> 2, scol = (lane & 3) * 8;
  const bool full = (tn >= 16);

  f32x4 acc[4][4];
  #pragma unroll
  for (int i = 0; i < 4; ++i)
    #pragma unroll
    for (int j = 0; j < 4; ++j) acc[i][j] = (f32x4){0.f, 0.f, 0.f, 0.f};

  const unsigned short* pAh = xh + (size_t)m0 * 1024;
  const unsigned short* pAl = xl + (size_t)m0 * 1024;
  const unsigned short* pBh = wfh + (size_t)(tn * 128) * 1024;
  const unsigned short* pBl = wfl + (size_t)(tn * 128) * 1024;

  auto stage = [&](const unsigned short* g, unsigned short* lds, int k0) {
    #pragma unroll
    for (int r = 0; r < 2; ++r) {
      const unsigned short* gp = g + (size_t)(r * 64 + wave * 16 + srow) * 1024 + k0 + scol;
      unsigned short* lp = lds + (r * 64 + wave * 16) * 32;
      __builtin_amdgcn_global_load_lds((const __attribute__((address_space(1))) void*)gp,
                                       (__attribute__((address_space(3))) void*)lp, 16, 0, 0);
    }
  };

  for (int k0 = 0; k0 < 1024; k0 += 32) {
    __syncthreads();
    stage(pAh, LAh, k0);
    stage(pAl, LAl, k0);
    stage(pBh, LBh, k0);
    if (full) stage(pBl, LBl, k0);
    __syncthreads();

    bf16x8 ah[4], al[4], bh[4];
    #pragma unroll
    for (int i = 0; i < 4; ++i) {
      const int ar = (wr * 64 + i * 16 + ln) * 32 + kq * 8;
      const int br = (wc * 64 + i * 16 + ln) * 32 + kq * 8;
      ah[i] = *(const bf16x8*)&LAh[ar];
      al[i] = *(const bf16x8*)&LAl[ar];
      bh[i] = *(const bf16x8*)&LBh[br];
    }
    if (full) {
      bf16x8 bl[4];
      #pragma unroll
      for (int i = 0; i < 4; ++i)
        bl[i] = *(const bf16x8*)&LBl[(wc * 64 + i * 16 + ln) * 32 + kq * 8];
      #pragma unroll
      for (int i = 0; i < 4; ++i)
        #pragma unroll
        for (int j = 0; j < 4; ++j) {
          acc[i][j] = __builtin_amdgcn_mfma_f32_16x16x32_bf16(ah[i], bh[j], acc[i][j], 0, 0, 0);
          acc[i][j] = __builtin_amdgcn_mfma_f32_16x16x32_bf16(ah[i], bl[j], acc[i][j], 0, 0, 0);
          acc[i][j] = __builtin_amdgcn_mfma_f32_16x16x32_bf16(al[i], bh[j], acc[i][j], 0, 0, 0);
        }
    } else {
      #pragma unroll
      for (int i = 0; i < 4; ++i)
        #pragma unroll
        for (int j = 0; j < 4; ++j) {
          acc[i][j] = __builtin_amdgcn_mfma_f32_16x16x32_bf16(ah[i], bh[j], acc[i][j], 0, 0, 0);
          acc[i][j] = __builtin_amdgcn_mfma_f32_16x16x32_bf16(al[i], bh[j], acc[i][j], 0, 0, 0);
        }
    }
  }

  // Epilogue. C/D layout: col = lane&15, row = (lane>>4)*4 + reg  [m89/m91]
  #pragma unroll
  for (int nj = 0; nj < 4; ++nj) {
    const int colg = tn * 128 + wc * 64 + nj * 16 + ln;
    const float bv = (tn < 16) ? b1[colg] : bfull[colg - 2048];
    #pragma unroll
    for (int mi = 0; mi < 4; ++mi) {
      const int row = m0 + wr * 64 + mi * 16 + kq * 4;
      #pragma unroll
      for (int j = 0; j < 4; ++j) {
        const float val = acc[mi][nj][j] + bv;
        if (tn < 8)       u_[(size_t)(row + j) * 1024 + colg] = val;
        else if (tn < 16) v_[(size_t)(row + j) * 1024 + colg - 1024] = val;
        else if (tn < 24) delta[(size_t)(row + j) * 1024 + colg - 2048] = softplus_f(val);
        else              Bm[(size_t)(row + j) * 128 + colg - 3072] = val;
      }
    }
  }
}

// ---------------------------------------------------------------------------
// Chunk-parallel selective scan with fused depthwise conv+silu.
// ---------------------------------------------------------------------------
__global__ __launch_bounds__(256) void k_scanA(
    const float* __restrict__ delta, const float* __restrict__ u_,
    const float* __restrict__ Bm, const float* __restrict__ a_log,
    const float* __restrict__ cw, const float* __restrict__ cb,
    float* __restrict__ hend, float* __restrict__ Pp)
{
  __shared__ float sru[68][SPAD];
  __shared__ float sd[CHK][SPAD];
  __shared__ float sb[CHK][SPAD];
  __shared__ float suc[CHK][SPAD];
  const int t = threadIdx.x;
  const int bid = blockIdx.x;
  const int dblk = bid & 63;
  const int ch   = (bid >> 6) & (NCH - 1);
  const int b    = bid >> 11;
  const int d0 = dblk * 16;
  const int g  = dblk >> 3;
  const int l0 = ch * CHK;
  const size_t mb = (size_t)b * LTOT;

  {
    const int lrow = t >> 2;
    const int lc4  = (t & 3) * 4;
    const size_t r = mb + l0 + lrow;
    float4 rd = *(const float4*)&delta[r*1024 + d0 + lc4];
    float4 rb = *(const float4*)&Bm[r*128 + g*16 + lc4];
    *(float4*)&sd[lrow][lc4] = rd;
    *(float4*)&sb[lrow][lc4] = rb;
    const int sl = l0 + lrow - 4;
    float4 ru = (sl >= 0) ? *(const float4*)&u_[(mb + sl)*1024 + d0 + lc4]
                          : (float4){0.f, 0.f, 0.f, 0.f};
    *(float4*)&sru[lrow][lc4] = ru;
    if (t < 16) {
      const int rr2 = 64 + (t >> 2);
      const int sl2 = l0 + rr2 - 4;
      float4 r2 = *(const float4*)&u_[(mb + sl2)*1024 + d0 + (t & 3) * 4];
      *(float4*)&sru[rr2][(t & 3) * 4] = r2;
    }
  }
  __syncthreads();
  {
    const int c = t & 15;
    const int rb4 = (t >> 4) * 4;
    const float4 cwf = *(const float4*)&cw[(d0 + c) * 4];
    const float cbf = cb[d0 + c];
    #pragma unroll
    for (int q = 0; q < 4; ++q) {
      const int l = rb4 + q;
      float a = cbf;
      a = fmaf(sru[l+1][c], cwf.x, a);
      a = fmaf(sru[l+2][c], cwf.y, a);
      a = fmaf(sru[l+3][c], cwf.z, a);
      a = fmaf(sru[l+4][c], cwf.w, a);
      suc[l][c] = silu_f(a);
    }
  }
  __syncthreads();

  const int gi = t >> 4;
  const int n  = t & 15;
  const int d  = d0 + gi;
  const float A2 = -expf(a_log[d*16 + n]) * 1.4426950408889634f;

  float h = 0.f, P = 1.f;
  #pragma unroll 8
  for (int l = 0; l < CHK; ++l) {
    const float dv = sd[l][gi];
    const float uv = suc[l][gi];
    const float bv = sb[l][n];
    const float da = exp2f(dv * A2);
    P *= da;
    h = fmaf(da, h, dv * uv * bv);
  }
  const size_t idx = ((size_t)(b*NCH + ch) * 1024 + d) * 16 + n;
  hend[idx] = h;
  Pp[idx]   = P;
}

__global__ void k_scanB(float* hP, const float* __restrict__ Pp)
{
  const int t = blockIdx.x * 256 + threadIdx.x;   // 32768 strands
  const int b  = t >> 14;
  const int dn = t & 16383;
  float H = 0.f;
  for (int ch = 0; ch < NCH; ++ch) {
    const size_t idx = ((size_t)(b*NCH + ch) << 14) + dn;
    const float he = hP[idx];
    const float P  = Pp[idx];
    hP[idx] = H;
    H = fmaf(P, H, he);
  }
}

__global__ __launch_bounds__(256) void k_scanC(
    const float* __restrict__ v_, const float* __restrict__ delta,
    const float* __restrict__ u_, const float* __restrict__ Bm,
    const float* __restrict__ a_log, const float* __restrict__ cp,
    const float* __restrict__ cw, const float* __restrict__ cb,
    const float* __restrict__ Hstart, float* __restrict__ out)
{
  __shared__ float sru[68][SPAD];
  __shared__ float sd[CHK][SPAD];
  __shared__ float sb[CHK][SPAD];
  __shared__ float suc[CHK][SPAD];
  __shared__ float sv[CHK][SPAD];
  __shared__ float sy[CHK][SPAD];
  const int t = threadIdx.x;
  const int bid = blockIdx.x;
  const int dblk = bid & 63;
  const int ch   = (bid >> 6) & (NCH - 1);
  const int b    = bid >> 11;
  const int d0 = dblk * 16;
  const int g  = dblk >> 3;
  const int l0 = ch * CHK;
  const size_t mb = (size_t)b * LTOT;

  {
    const int lrow = t >> 2;
    const int lc4  = (t & 3) * 4;
    const size_t r = mb + l0 + lrow;
    float4 rd = *(const float4*)&delta[r*1024 + d0 + lc4];
    float4 rb = *(const float4*)&Bm[r*128 + g*16 + lc4];
    float4 rv = *(const float4*)&v_[r*1024 + d0 + lc4];
    *(float4*)&sd[lrow][lc4] = rd;
    *(float4*)&sb[lrow][lc4] = rb;
    *(float4*)&sv[lrow][lc4] = rv;
    const int sl = l0 + lrow - 4;
    float4 ru = (sl >= 0) ? *(const float4*)&u_[(mb + sl)*1024 + d0 + lc4]
                          : (float4){0.f, 0.f, 0.f, 0.f};
    *(float4*)&sru[lrow][lc4] = ru;
    if (t < 16) {
      const int rr2 = 64 + (t >> 2);
      const int sl2 = l0 + rr2 - 4;
      float4 r2 = *(const float4*)&u_[(mb + sl2)*1024 + d0 + (t & 3) * 4];
      *(float4*)&sru[rr2][(t & 3) * 4] = r2;
    }
  }
  __syncthreads();
  {
    const int c = t & 15;
    const int rb4 = (t >> 4) * 4;
    const float4 cwf = *(const float4*)&cw[(d0 + c) * 4];
    const float cbf = cb[d0 + c];
    #pragma unroll
    for (int q = 0; q < 4; ++q) {
      const int l = rb4 + q;
      float a = cbf;
      a = fmaf(sru[l+1][c], cwf.x, a);
      a = fmaf(sru[l+2][c], cwf.y, a);
      a = fmaf(sru[l+3][c], cwf.z, a);
      a = fmaf(sru[l+4][c], cwf.w, a);
      suc[l][c] = silu_f(a);
    }
  }
  __syncthreads();

  const int gi = t >> 4;
  const int n  = t & 15;
  const int d  = d0 + gi;
  const float A2 = -expf(a_log[d*16 + n]) * 1.4426950408889634f;
  const float cc = cp[d*16 + n];
  float h = Hstart[((size_t)(b*NCH + ch) * 1024 + d) * 16 + n];

  #pragma unroll
  for (int l16 = 0; l16 < CHK; l16 += 16) {
    float p[16];
    #pragma unroll
    for (int j = 0; j < 16; ++j) {
      const int l = l16 + j;
      const float dv = sd[l][gi];
      const float uv = suc[l][gi];
      const float bv = sb[l][n];
      const float da = exp2f(dv * A2);
      h = fmaf(da, h, dv * uv * bv);
      p[j] = h * cc;
    }
    float q8[8];
    #pragma unroll
    for (int j = 0; j < 8; ++j) {
      const float send = (n & 8) ? p[j]     : p[j + 8];
      const float keep = (n & 8) ? p[j + 8] : p[j];
      q8[j] = keep + __shfl_xor(send, 8, 16);
    }
    float q4[4];
    #pragma unroll
    for (int j = 0; j < 4; ++j) {
      const float send = (n & 4) ? q8[j]     : q8[j + 4];
      const float keep = (n & 4) ? q8[j + 4] : q8[j];
      q4[j] = keep + __shfl_xor(send, 4, 16);
    }
    float q2[2];
    #pragma unroll
    for (int j = 0; j < 2; ++j) {
      const float send = (n & 2) ? q4[j]     : q4[j + 2];
      const float keep = (n & 2) ? q4[j + 2] : q4[j];
      q2[j] = keep + __shfl_xor(send, 2, 16);
    }
    {
      const float send = (n & 1) ? q2[0] : q2[1];
      const float keep = (n & 1) ? q2[1] : q2[0];
      sy[l16 + n][gi] = keep + __shfl_xor(send, 1, 16);
    }
  }

  __syncthreads();
  const int rr = t >> 4;
  const int c  = t & 15;
  #pragma unroll
  for (int k = 0; k < 4; ++k) {
    const int r = rr + k * 16;
    const float vv = sv[r][c];
    out[(mb + l0 + r) * 1024 + d0 + c] = sy[r][c] * silu_f(vv);
  }
}

// ---------------------------------------------------------------------------
extern "C" void kernel_launch(void* const* d_in, const int* in_sizes, int n_in,
                              void* d_out, int out_size, void* d_ws, size_t ws_size,
                              hipStream_t stream) {
  const float* x    = (const float*)d_in[0];
  const float* w1   = (const float*)d_in[1];
  const float* b1   = (const float*)d_in[2];
  const float* dw   = (const float*)d_in[3];
  const float* alog = (const float*)d_in[4];
  const float* bw   = (const float*)d_in[5];
  const float* bb   = (const float*)d_in[6];
  const float* cp   = (const float*)d_in[7];
  const float* cw   = (const float*)d_in[8];
  const float* cb   = (const float*)d_in[9];
  float* out = (float*)d_out;

  const size_t M4 = (size_t)MROWS * 1024;             // 4,194,304
  float* u_    = (float*)d_ws;                        // [4096][1024] 16 MB
  float* v_    = u_ + M4;                             // 16 MB
  float* delta = v_ + M4;                             // 16 MB
  float* Bm    = delta + M4;                          // [4096][128]   2 MB
  unsigned short* xh  = (unsigned short*)(Bm + (size_t)MROWS * 128);
  unsigned short* xl  = xh + M4;
  unsigned short* wfh = xl + M4;                      // [3200][1024]  6.25 MB
  unsigned short* wfl = wfh + (size_t)3200 * 1024;
  float* bfull = (float*)(wfl + (size_t)3200 * 1024); // [1152]
  // pre-main aliases (dead before their regions are written):
  unsigned short* wdbAh = (unsigned short*)delta;     // [1152][1024] in delta region
  unsigned short* wdbAl = wdbAh + (size_t)1152 * 1024;
  unsigned short* w1th  = wdbAl + (size_t)1152 * 1024;
  unsigned short* w1tl  = w1th + (size_t)1024 * 1024; // total 8.5 MB <= 16 MB
  // post-main aliases (wfull dead after k_main):
  float* hend = (float*)wfh;                          // 4 MB
  float* Pp   = hend + (size_t)2 * NCH * 1024 * 16;   // 4 MB (<= 12.5 MB region)

  k_cvt<<<4096, 256, 0, stream>>>(x,  xh, xl, 1048576);
  k_cvt<<<2048, 256, 0, stream>>>(w1, wfh, wfl, 524288);
  k_cvt<<<1024, 256, 0, stream>>>(dw, wdbAh, wdbAl, 262144);
  k_cvt<<<128, 256, 0, stream>>>(bw, wdbAh + (size_t)1024*1024, wdbAl + (size_t)1024*1024, 32768);
  k_cvt_t<<<dim3(16, 16), 256, 0, stream>>>(w1, w1th, w1tl);
  k_bias<<<72, 256, 0, stream>>>(b1, dw, bw, bb, bfull);
  k_wcomp<<<dim3(16, 18), 256, 0, stream>>>(wdbAh, wdbAl, w1th, w1tl,
                                            wfh + (size_t)2048*1024, wfl + (size_t)2048*1024);
  k_main<<<dim3(25, 32), 256, 0, stream>>>(xh, xl, wfh, wfl, b1, bfull, u_, v_, delta, Bm);
  k_scanA<<<2 * NCH * 64, 256, 0, stream>>>(delta, u_, Bm, alog, cw, cb, hend, Pp);
  k_scanB<<<128, 256, 0, stream>>>(hend, Pp);
  k_scanC<<<2 * NCH * 64, 256, 0, stream>>>(v_, delta, u_, Bm, alog, cp, cw, cb, hend, out);
}

// Round 6
// 229.053 us; speedup vs baseline: 1.1717x; 1.0705x over previous
//
#include <hip/hip_runtime.h>
#include <math.h>

#define LTOT 2048
#define MROWS 4096   // BATCH * LTOT
#define CHK 64
#define NCH (LTOT / CHK)   // 32
#define SPAD 20

typedef short bf16x8 __attribute__((ext_vector_type(8)));
typedef float f32x4  __attribute__((ext_vector_type(4)));
typedef float f32x16 __attribute__((ext_vector_type(16)));

__device__ __forceinline__ unsigned short bf16_rne(float f) {
  unsigned u = __float_as_uint(f);
  u += 0x7FFF + ((u >> 16) & 1);
  return (unsigned short)(u >> 16);
}
__device__ __forceinline__ float bf16_to_f(unsigned short h) {
  return __uint_as_float(((unsigned)h) << 16);
}
__device__ __forceinline__ float softplus_f(float x) {
  return (x > 15.f) ? x : log1pf(expf(x));
}
__device__ __forceinline__ float silu_f(float x) {
  return x / (1.f + expf(-x));
}

// ---------------------------------------------------------------------------
// Merged fp32 -> (hi,lo) bf16 split for x, w1, dw, bw (one launch).
// Segments by blockIdx: [0,4096) x, [4096,6144) w1, [6144,7168) dw, [7168,7296) bw.
// ---------------------------------------------------------------------------
__global__ void k_cvt_all(const float* __restrict__ x, const float* __restrict__ w1,
                          const float* __restrict__ dw, const float* __restrict__ bw,
                          unsigned short* __restrict__ xh, unsigned short* __restrict__ xl,
                          unsigned short* __restrict__ wfh, unsigned short* __restrict__ wfl,
                          unsigned short* __restrict__ wdbAh, unsigned short* __restrict__ wdbAl) {
  const int blk = blockIdx.x;
  const float* src; unsigned short *h, *l; int i;
  if (blk < 4096)      { src = x;  h = xh;  l = xl;  i = blk * 256 + threadIdx.x; }
  else if (blk < 6144) { src = w1; h = wfh; l = wfl; i = (blk - 4096) * 256 + threadIdx.x; }
  else if (blk < 7168) { src = dw; h = wdbAh; l = wdbAl; i = (blk - 6144) * 256 + threadIdx.x; }
  else                 { src = bw; h = wdbAh + (size_t)1024*1024; l = wdbAl + (size_t)1024*1024;
                         i = (blk - 7168) * 256 + threadIdx.x; }
  const float4 v = ((const float4*)src)[i];
  ushort4 hh, ll;
  hh.x = bf16_rne(v.x); ll.x = bf16_rne(v.x - bf16_to_f(hh.x));
  hh.y = bf16_rne(v.y); ll.y = bf16_rne(v.y - bf16_to_f(hh.y));
  hh.z = bf16_rne(v.z); ll.z = bf16_rne(v.z - bf16_to_f(hh.z));
  hh.w = bf16_rne(v.w); ll.w = bf16_rne(v.w - bf16_to_f(hh.w));
  ((ushort4*)h)[i] = hh;
  ((ushort4*)l)[i] = ll;
}

// ---------------------------------------------------------------------------
// Transposed split of W1u: out[k][j] = W1[j][k], j,k < 1024, hi/lo bf16.
// ---------------------------------------------------------------------------
__global__ __launch_bounds__(256) void k_cvt_t(const float* __restrict__ w1,
    unsigned short* __restrict__ th, unsigned short* __restrict__ tl) {
  __shared__ float ts[64][65];
  const int t = threadIdx.x;
  const int j0 = blockIdx.y * 64, k0 = blockIdx.x * 64;
  const int r = t >> 4, c4 = (t & 15) * 4;
  #pragma unroll
  for (int p = 0; p < 4; ++p) {
    const int row = p * 16 + r;
    const float4 v = *(const float4*)&w1[(size_t)(j0 + row) * 1024 + k0 + c4];
    ts[row][c4] = v.x; ts[row][c4+1] = v.y; ts[row][c4+2] = v.z; ts[row][c4+3] = v.w;
  }
  __syncthreads();
  #pragma unroll
  for (int p = 0; p < 4; ++p) {
    const int rk = p * 16 + r;
    ushort4 hh, ll;
    float f;
    f = ts[c4+0][rk]; hh.x = bf16_rne(f); ll.x = bf16_rne(f - bf16_to_f(hh.x));
    f = ts[c4+1][rk]; hh.y = bf16_rne(f); ll.y = bf16_rne(f - bf16_to_f(hh.y));
    f = ts[c4+2][rk]; hh.z = bf16_rne(f); ll.z = bf16_rne(f - bf16_to_f(hh.z));
    f = ts[c4+3][rk]; hh.w = bf16_rne(f); ll.w = bf16_rne(f - bf16_to_f(hh.w));
    *(ushort4*)&th[(size_t)(k0 + rk) * 1024 + j0 + c4] = hh;
    *(ushort4*)&tl[(size_t)(k0 + rk) * 1024 + j0 + c4] = ll;
  }
}

// ---------------------------------------------------------------------------
// bfull[j] = sum_k b1[k] * Wdb[j,k] + (j>=1024 ? bb[j-1024] : 0),  j < 1152
// ---------------------------------------------------------------------------
__global__ void k_bias(const float* __restrict__ b1, const float* __restrict__ dw,
                       const float* __restrict__ bw, const float* __restrict__ bb,
                       float* __restrict__ bfull) {
  const int t = threadIdx.x;
  const int j = blockIdx.x * 16 + (t >> 4);
  const int lane16 = t & 15;
  const float* W = (j < 1024) ? (dw + (size_t)j * 1024) : (bw + (size_t)(j - 1024) * 1024);
  float s = 0.f;
  for (int i = 0; i < 64; ++i) {
    const int k = lane16 + i * 16;
    s = fmaf(b1[k], W[k], s);
  }
  s += __shfl_xor(s, 8, 16);
  s += __shfl_xor(s, 4, 16);
  s += __shfl_xor(s, 2, 16);
  s += __shfl_xor(s, 1, 16);
  if (lane16 == 0) bfull[j] = s + ((j >= 1024) ? bb[j - 1024] : 0.f);
}

// ---------------------------------------------------------------------------
// Weight composition GEMM: C[i,k] = sum_j Wdb[i,j] * W1uT[k,j]  (split bf16 out)
// M=1152, N=1024, K=1024. 64x64 tiles, 4 waves of 32x32. grid (16, 18).
// ---------------------------------------------------------------------------
__global__ __launch_bounds__(256) void k_wcomp(
    const unsigned short* __restrict__ Ah_g, const unsigned short* __restrict__ Al_g,
    const unsigned short* __restrict__ Bh_g, const unsigned short* __restrict__ Bl_g,
    unsigned short* __restrict__ outh, unsigned short* __restrict__ outl) {
  __shared__ __align__(16) unsigned short LAh[64*32];
  __shared__ __align__(16) unsigned short LAl[64*32];
  __shared__ __align__(16) unsigned short LBh[64*32];
  __shared__ __align__(16) unsigned short LBl[64*32];
  const int t = threadIdx.x;
  const int wave = t >> 6, lane = t & 63;
  const int m0 = blockIdx.y * 64, n0 = blockIdx.x * 64;
  const int wr = wave >> 1, wc = wave & 1;
  const int l32 = lane & 31, hi = lane >> 5;
  const int srow = lane >> 2, scol = (lane & 3) * 8;

  f32x16 acc;
  #pragma unroll
  for (int q = 0; q < 16; ++q) acc[q] = 0.f;

  auto stage = [&](const unsigned short* g, unsigned short* lds, int rbase, int k0) {
    const unsigned short* gp = g + (size_t)(rbase + wave * 16 + srow) * 1024 + k0 + scol;
    unsigned short* lp = lds + (wave * 16) * 32;
    __builtin_amdgcn_global_load_lds((const __attribute__((address_space(1))) void*)gp,
                                     (__attribute__((address_space(3))) void*)lp, 16, 0, 0);
  };

  for (int k0 = 0; k0 < 1024; k0 += 32) {
    __syncthreads();
    stage(Ah_g, LAh, m0, k0);
    stage(Al_g, LAl, m0, k0);
    stage(Bh_g, LBh, n0, k0);
    stage(Bl_g, LBl, n0, k0);
    __syncthreads();
    #pragma unroll
    for (int kh = 0; kh < 2; ++kh) {
      const int ai = (wr * 32 + l32) * 32 + kh * 16 + hi * 8;
      const int bi = (wc * 32 + l32) * 32 + kh * 16 + hi * 8;
      bf16x8 a_h = *(const bf16x8*)&LAh[ai];
      bf16x8 a_l = *(const bf16x8*)&LAl[ai];
      bf16x8 b_h = *(const bf16x8*)&LBh[bi];
      bf16x8 b_l = *(const bf16x8*)&LBl[bi];
      acc = __builtin_amdgcn_mfma_f32_32x32x16_bf16(a_h, b_h, acc, 0, 0, 0);
      acc = __builtin_amdgcn_mfma_f32_32x32x16_bf16(a_h, b_l, acc, 0, 0, 0);
      acc = __builtin_amdgcn_mfma_f32_32x32x16_bf16(a_l, b_h, acc, 0, 0, 0);
    }
  }

  #pragma unroll
  for (int reg = 0; reg < 16; ++reg) {
    const int i = m0 + wr * 32 + (reg & 3) + 8 * (reg >> 2) + 4 * hi;
    const int k = n0 + wc * 32 + l32;
    const float f = acc[reg];
    const unsigned short hh = bf16_rne(f);
    const unsigned short ll = bf16_rne(f - bf16_to_f(hh));
    outh[(size_t)i * 1024 + k] = hh;
    outl[(size_t)i * 1024 + k] = ll;
  }
}

// ---------------------------------------------------------------------------
// Main GEMM: C = x . Wfull^T, Wfull = [W_in(2048) ; Wd'(1024) ; Wb'(128)], N=3200
// 128x128 tile, BK=32, 4 waves (2x2), 4x4 frags of 16x16x32.
// tn<16 (u,v): single product Ah*Bh (linear error path -> bf16 suffices).
// tn>=16 (delta,B): full 3-product split (exp(dA) amplifies by |A|<=16).
// Grid: 800 blocks 1D, bijective XCD-chunked swizzle (800 = 8*100) so each
// XCD owns 4 contiguous m-panels -> A stays L2-resident per XCD.
// ---------------------------------------------------------------------------
__global__ __launch_bounds__(256) void k_main(
    const unsigned short* __restrict__ xh, const unsigned short* __restrict__ xl,
    const unsigned short* __restrict__ wfh, const unsigned short* __restrict__ wfl,
    const float* __restrict__ b1, const float* __restrict__ bfull,
    float* __restrict__ u_, float* __restrict__ v_,
    float* __restrict__ delta, float* __restrict__ Bm) {
  __shared__ __align__(16) unsigned short LAh[128*32];
  __shared__ __align__(16) unsigned short LAl[128*32];
  __shared__ __align__(16) unsigned short LBh[128*32];
  __shared__ __align__(16) unsigned short LBl[128*32];
  const int t = threadIdx.x;
  const int wave = t >> 6, lane = t & 63;
  // XCD swizzle: contiguous chunks of 100 wgids per XCD, wgid in tn-major order
  const int flat = blockIdx.x;
  const int wg = (flat & 7) * 100 + (flat >> 3);
  const int tn = wg % 25;
  const int m0 = (wg / 25) * 128;
  const int wr = wave >> 1, wc = wave & 1;
  const int ln = lane & 15, kq = lane >> 4;
  const int srow = lane >> 2, scol = (lane & 3) * 8;
  const bool full = (tn >= 16);

  f32x4 acc[4][4];
  #pragma unroll
  for (int i = 0; i < 4; ++i)
    #pragma unroll
    for (int j = 0; j < 4; ++j) acc[i][j] = (f32x4){0.f, 0.f, 0.f, 0.f};

  const unsigned short* pAh = xh + (size_t)m0 * 1024;
  const unsigned short* pAl = xl + (size_t)m0 * 1024;
  const unsigned short* pBh = wfh + (size_t)(tn * 128) * 1024;
  const unsigned short* pBl = wfl + (size_t)(tn * 128) * 1024;

  auto stage = [&](const unsigned short* g, unsigned short* lds, int k0) {
    #pragma unroll
    for (int r = 0; r < 2; ++r) {
      const unsigned short* gp = g + (size_t)(r * 64 + wave * 16 + srow) * 1024 + k0 + scol;
      unsigned short* lp = lds + (r * 64 + wave * 16) * 32;
      __builtin_amdgcn_global_load_lds((const __attribute__((address_space(1))) void*)gp,
                                       (__attribute__((address_space(3))) void*)lp, 16, 0, 0);
    }
  };

  for (int k0 = 0; k0 < 1024; k0 += 32) {
    __syncthreads();
    stage(pAh, LAh, k0);
    stage(pBh, LBh, k0);
    if (full) { stage(pAl, LAl, k0); stage(pBl, LBl, k0); }
    __syncthreads();

    if (full) {
      bf16x8 ah[4], al[4], bh[4], bl[4];
      #pragma unroll
      for (int i = 0; i < 4; ++i) {
        const int ar = (wr * 64 + i * 16 + ln) * 32 + kq * 8;
        const int br = (wc * 64 + i * 16 + ln) * 32 + kq * 8;
        ah[i] = *(const bf16x8*)&LAh[ar];
        al[i] = *(const bf16x8*)&LAl[ar];
        bh[i] = *(const bf16x8*)&LBh[br];
        bl[i] = *(const bf16x8*)&LBl[br];
      }
      #pragma unroll
      for (int i = 0; i < 4; ++i)
        #pragma unroll
        for (int j = 0; j < 4; ++j) {
          acc[i][j] = __builtin_amdgcn_mfma_f32_16x16x32_bf16(ah[i], bh[j], acc[i][j], 0, 0, 0);
          acc[i][j] = __builtin_amdgcn_mfma_f32_16x16x32_bf16(ah[i], bl[j], acc[i][j], 0, 0, 0);
          acc[i][j] = __builtin_amdgcn_mfma_f32_16x16x32_bf16(al[i], bh[j], acc[i][j], 0, 0, 0);
        }
    } else {
      bf16x8 ah[4], bh[4];
      #pragma unroll
      for (int i = 0; i < 4; ++i) {
        const int ar = (wr * 64 + i * 16 + ln) * 32 + kq * 8;
        const int br = (wc * 64 + i * 16 + ln) * 32 + kq * 8;
        ah[i] = *(const bf16x8*)&LAh[ar];
        bh[i] = *(const bf16x8*)&LBh[br];
      }
      #pragma unroll
      for (int i = 0; i < 4; ++i)
        #pragma unroll
        for (int j = 0; j < 4; ++j)
          acc[i][j] = __builtin_amdgcn_mfma_f32_16x16x32_bf16(ah[i], bh[j], acc[i][j], 0, 0, 0);
    }
  }

  // Epilogue. C/D layout: col = lane&15, row = (lane>>4)*4 + reg  [m89/m91]
  #pragma unroll
  for (int nj = 0; nj < 4; ++nj) {
    const int colg = tn * 128 + wc * 64 + nj * 16 + ln;
    const float bv = (tn < 16) ? b1[colg] : bfull[colg - 2048];
    #pragma unroll
    for (int mi = 0; mi < 4; ++mi) {
      const int row = m0 + wr * 64 + mi * 16 + kq * 4;
      #pragma unroll
      for (int j = 0; j < 4; ++j) {
        const float val = acc[mi][nj][j] + bv;
        if (tn < 8)       u_[(size_t)(row + j) * 1024 + colg] = val;
        else if (tn < 16) v_[(size_t)(row + j) * 1024 + colg - 1024] = val;
        else if (tn < 24) delta[(size_t)(row + j) * 1024 + colg - 2048] = softplus_f(val);
        else              Bm[(size_t)(row + j) * 128 + colg - 3072] = val;
      }
    }
  }
}

// ---------------------------------------------------------------------------
// Chunk-parallel selective scan with fused depthwise conv+silu.
// ---------------------------------------------------------------------------
__global__ __launch_bounds__(256) void k_scanA(
    const float* __restrict__ delta, const float* __restrict__ u_,
    const float* __restrict__ Bm, const float* __restrict__ a_log,
    const float* __restrict__ cw, const float* __restrict__ cb,
    float* __restrict__ hend, float* __restrict__ Pp)
{
  __shared__ float sru[68][SPAD];
  __shared__ float sd[CHK][SPAD];
  __shared__ float sb[CHK][SPAD];
  __shared__ float suc[CHK][SPAD];
  const int t = threadIdx.x;
  const int bid = blockIdx.x;
  const int dblk = bid & 63;
  const int ch   = (bid >> 6) & (NCH - 1);
  const int b    = bid >> 11;
  const int d0 = dblk * 16;
  const int g  = dblk >> 3;
  const int l0 = ch * CHK;
  const size_t mb = (size_t)b * LTOT;

  {
    const int lrow = t >> 2;
    const int lc4  = (t & 3) * 4;
    const size_t r = mb + l0 + lrow;
    float4 rd = *(const float4*)&delta[r*1024 + d0 + lc4];
    float4 rb = *(const float4*)&Bm[r*128 + g*16 + lc4];
    *(float4*)&sd[lrow][lc4] = rd;
    *(float4*)&sb[lrow][lc4] = rb;
    const int sl = l0 + lrow - 4;
    float4 ru = (sl >= 0) ? *(const float4*)&u_[(mb + sl)*1024 + d0 + lc4]
                          : (float4){0.f, 0.f, 0.f, 0.f};
    *(float4*)&sru[lrow][lc4] = ru;
    if (t < 16) {
      const int rr2 = 64 + (t >> 2);
      const int sl2 = l0 + rr2 - 4;
      float4 r2 = *(const float4*)&u_[(mb + sl2)*1024 + d0 + (t & 3) * 4];
      *(float4*)&sru[rr2][(t & 3) * 4] = r2;
    }
  }
  __syncthreads();
  {
    const int c = t & 15;
    const int rb4 = (t >> 4) * 4;
    const float4 cwf = *(const float4*)&cw[(d0 + c) * 4];
    const float cbf = cb[d0 + c];
    #pragma unroll
    for (int q = 0; q < 4; ++q) {
      const int l = rb4 + q;
      float a = cbf;
      a = fmaf(sru[l+1][c], cwf.x, a);
      a = fmaf(sru[l+2][c], cwf.y, a);
      a = fmaf(sru[l+3][c], cwf.z, a);
      a = fmaf(sru[l+4][c], cwf.w, a);
      suc[l][c] = silu_f(a);
    }
  }
  __syncthreads();

  const int gi = t >> 4;
  const int n  = t & 15;
  const int d  = d0 + gi;
  const float A2 = -expf(a_log[d*16 + n]) * 1.4426950408889634f;

  float h = 0.f, P = 1.f;
  #pragma unroll 8
  for (int l = 0; l < CHK; ++l) {
    const float dv = sd[l][gi];
    const float uv = suc[l][gi];
    const float bv = sb[l][n];
    const float da = exp2f(dv * A2);
    P *= da;
    h = fmaf(da, h, dv * uv * bv);
  }
  const size_t idx = ((size_t)(b*NCH + ch) * 1024 + d) * 16 + n;
  hend[idx] = h;
  Pp[idx]   = P;
}

__global__ void k_scanB(float* hP, const float* __restrict__ Pp)
{
  const int t = blockIdx.x * 256 + threadIdx.x;   // 32768 strands
  const int b  = t >> 14;
  const int dn = t & 16383;
  float H = 0.f;
  for (int ch = 0; ch < NCH; ++ch) {
    const size_t idx = ((size_t)(b*NCH + ch) << 14) + dn;
    const float he = hP[idx];
    const float P  = Pp[idx];
    hP[idx] = H;
    H = fmaf(P, H, he);
  }
}

__global__ __launch_bounds__(256) void k_scanC(
    const float* __restrict__ v_, const float* __restrict__ delta,
    const float* __restrict__ u_, const float* __restrict__ Bm,
    const float* __restrict__ a_log, const float* __restrict__ cp,
    const float* __restrict__ cw, const float* __restrict__ cb,
    const float* __restrict__ Hstart, float* __restrict__ out)
{
  __shared__ float sru[68][SPAD];
  __shared__ float sd[CHK][SPAD];
  __shared__ float sb[CHK][SPAD];
  __shared__ float suc[CHK][SPAD];
  __shared__ float sv[CHK][SPAD];
  __shared__ float sy[CHK][SPAD];
  const int t = threadIdx.x;
  const int bid = blockIdx.x;
  const int dblk = bid & 63;
  const int ch   = (bid >> 6) & (NCH - 1);
  const int b    = bid >> 11;
  const int d0 = dblk * 16;
  const int g  = dblk >> 3;
  const int l0 = ch * CHK;
  const size_t mb = (size_t)b * LTOT;

  {
    const int lrow = t >> 2;
    const int lc4  = (t & 3) * 4;
    const size_t r = mb + l0 + lrow;
    float4 rd = *(const float4*)&delta[r*1024 + d0 + lc4];
    float4 rb = *(const float4*)&Bm[r*128 + g*16 + lc4];
    float4 rv = *(const float4*)&v_[r*1024 + d0 + lc4];
    *(float4*)&sd[lrow][lc4] = rd;
    *(float4*)&sb[lrow][lc4] = rb;
    *(float4*)&sv[lrow][lc4] = rv;
    const int sl = l0 + lrow - 4;
    float4 ru = (sl >= 0) ? *(const float4*)&u_[(mb + sl)*1024 + d0 + lc4]
                          : (float4){0.f, 0.f, 0.f, 0.f};
    *(float4*)&sru[lrow][lc4] = ru;
    if (t < 16) {
      const int rr2 = 64 + (t >> 2);
      const int sl2 = l0 + rr2 - 4;
      float4 r2 = *(const float4*)&u_[(mb + sl2)*1024 + d0 + (t & 3) * 4];
      *(float4*)&sru[rr2][(t & 3) * 4] = r2;
    }
  }
  __syncthreads();
  {
    const int c = t & 15;
    const int rb4 = (t >> 4) * 4;
    const float4 cwf = *(const float4*)&cw[(d0 + c) * 4];
    const float cbf = cb[d0 + c];
    #pragma unroll
    for (int q = 0; q < 4; ++q) {
      const int l = rb4 + q;
      float a = cbf;
      a = fmaf(sru[l+1][c], cwf.x, a);
      a = fmaf(sru[l+2][c], cwf.y, a);
      a = fmaf(sru[l+3][c], cwf.z, a);
      a = fmaf(sru[l+4][c], cwf.w, a);
      suc[l][c] = silu_f(a);
    }
  }
  __syncthreads();

  const int gi = t >> 4;
  const int n  = t & 15;
  const int d  = d0 + gi;
  const float A2 = -expf(a_log[d*16 + n]) * 1.4426950408889634f;
  const float cc = cp[d*16 + n];
  float h = Hstart[((size_t)(b*NCH + ch) * 1024 + d) * 16 + n];

  #pragma unroll
  for (int l16 = 0; l16 < CHK; l16 += 16) {
    float p[16];
    #pragma unroll
    for (int j = 0; j < 16; ++j) {
      const int l = l16 + j;
      const float dv = sd[l][gi];
      const float uv = suc[l][gi];
      const float bv = sb[l][n];
      const float da = exp2f(dv * A2);
      h = fmaf(da, h, dv * uv * bv);
      p[j] = h * cc;
    }
    float q8[8];
    #pragma unroll
    for (int j = 0; j < 8; ++j) {
      const float send = (n & 8) ? p[j]     : p[j + 8];
      const float keep = (n & 8) ? p[j + 8] : p[j];
      q8[j] = keep + __shfl_xor(send, 8, 16);
    }
    float q4[4];
    #pragma unroll
    for (int j = 0; j < 4; ++j) {
      const float send = (n & 4) ? q8[j]     : q8[j + 4];
      const float keep = (n & 4) ? q8[j + 4] : q8[j];
      q4[j] = keep + __shfl_xor(send, 4, 16);
    }
    float q2[2];
    #pragma unroll
    for (int j = 0; j < 2; ++j) {
      const float send = (n & 2) ? q4[j]     : q4[j + 2];
      const float keep = (n & 2) ? q4[j + 2] : q4[j];
      q2[j] = keep + __shfl_xor(send, 2, 16);
    }
    {
      const float send = (n & 1) ? q2[0] : q2[1];
      const float keep = (n & 1) ? q2[1] : q2[0];
      sy[l16 + n][gi] = keep + __shfl_xor(send, 1, 16);
    }
  }

  __syncthreads();
  const int rr = t >> 4;
  const int c  = t & 15;
  #pragma unroll
  for (int k = 0; k < 4; ++k) {
    const int r = rr + k * 16;
    const float vv = sv[r][c];
    out[(mb + l0 + r) * 1024 + d0 + c] = sy[r][c] * silu_f(vv);
  }
}

// ---------------------------------------------------------------------------
extern "C" void kernel_launch(void* const* d_in, const int* in_sizes, int n_in,
                              void* d_out, int out_size, void* d_ws, size_t ws_size,
                              hipStream_t stream) {
  const float* x    = (const float*)d_in[0];
  const float* w1   = (const float*)d_in[1];
  const float* b1   = (const float*)d_in[2];
  const float* dw   = (const float*)d_in[3];
  const float* alog = (const float*)d_in[4];
  const float* bw   = (const float*)d_in[5];
  const float* bb   = (const float*)d_in[6];
  const float* cp   = (const float*)d_in[7];
  const float* cw   = (const float*)d_in[8];
  const float* cb   = (const float*)d_in[9];
  float* out = (float*)d_out;

  const size_t M4 = (size_t)MROWS * 1024;             // 4,194,304
  float* u_    = (float*)d_ws;                        // [4096][1024] 16 MB
  float* v_    = u_ + M4;                             // 16 MB
  float* delta = v_ + M4;                             // 16 MB
  float* Bm    = delta + M4;                          // [4096][128]   2 MB
  unsigned short* xh  = (unsigned short*)(Bm + (size_t)MROWS * 128);
  unsigned short* xl  = xh + M4;
  unsigned short* wfh = xl + M4;                      // [3200][1024]  6.25 MB
  unsigned short* wfl = wfh + (size_t)3200 * 1024;
  float* bfull = (float*)(wfl + (size_t)3200 * 1024); // [1152]
  // pre-main aliases (dead before their regions are written):
  unsigned short* wdbAh = (unsigned short*)delta;     // [1152][1024] in delta region
  unsigned short* wdbAl = wdbAh + (size_t)1152 * 1024;
  unsigned short* w1th  = wdbAl + (size_t)1152 * 1024;
  unsigned short* w1tl  = w1th + (size_t)1024 * 1024; // total 8.5 MB <= 16 MB
  // post-main aliases (wfull dead after k_main):
  float* hend = (float*)wfh;                          // 4 MB
  float* Pp   = hend + (size_t)2 * NCH * 1024 * 16;   // 4 MB (<= 12.5 MB region)

  k_cvt_all<<<7296, 256, 0, stream>>>(x, w1, dw, bw, xh, xl, wfh, wfl, wdbAh, wdbAl);
  k_cvt_t<<<dim3(16, 16), 256, 0, stream>>>(w1, w1th, w1tl);
  k_bias<<<72, 256, 0, stream>>>(b1, dw, bw, bb, bfull);
  k_wcomp<<<dim3(16, 18), 256, 0, stream>>>(wdbAh, wdbAl, w1th, w1tl,
                                            wfh + (size_t)2048*1024, wfl + (size_t)2048*1024);
  k_main<<<800, 256, 0, stream>>>(xh, xl, wfh, wfl, b1, bfull, u_, v_, delta, Bm);
  k_scanA<<<2 * NCH * 64, 256, 0, stream>>>(delta, u_, Bm, alog, cw, cb, hend, Pp);
  k_scanB<<<128, 256, 0, stream>>>(hend, Pp);
  k_scanC<<<2 * NCH * 64, 256, 0, stream>>>(v_, delta, u_, Bm, alog, cp, cw, cb, hend, out);
}